// Round 4
// baseline (1313.671 us; speedup 1.0000x reference)
//
#include <hip/hip_runtime.h>

typedef unsigned short u16;
typedef unsigned int u32;

constexpr int N_ = 10240, E_ = 81920, B_ = 512, S_ = 20, V_ = 100000, D_ = 256;
constexpr float SCALE_ = 12.0f;

#define DEV static __device__ __forceinline__

typedef __attribute__((ext_vector_type(8))) short bf16x8;
typedef __attribute__((ext_vector_type(4))) float f32x4;

DEV float bf2f(u16 u){ union{u32 i; float f;} c; c.i = ((u32)u)<<16; return c.f; }
DEV float bflo(u32 u){ union{u32 i; float f;} c; c.i = u<<16; return c.f; }
DEV float bfhi(u32 u){ union{u32 i; float f;} c; c.i = u & 0xffff0000u; return c.f; }
DEV u16 f2bf(float f){ union{float f; u32 i;} c; c.f=f; u32 i=c.i; i += 0x7fffu + ((i>>16)&1u); return (u16)(i>>16); }
DEV float clampf(float x, float lo, float hi){ return fminf(fmaxf(x, lo), hi); } // NaN -> lo

// dtype-dispatched scalar load of float input
DEV float ldf(const void* p, size_t idx, int isf32){
  return isf32 ? ((const float*)p)[idx] : bf2f(((const u16*)p)[idx]);
}
DEV float rdout(const void* p, size_t idx, int isf32){
  return isf32 ? ((const float*)p)[idx] : bf2f(((const u16*)p)[idx]);
}
DEV void stout(void* p, size_t idx, float v, int isf32){
  if (isf32) ((float*)p)[idx] = v; else ((u16*)p)[idx] = f2bf(v);
}

DEV float waveSum(float v){
  #pragma unroll
  for (int off=32; off>0; off>>=1) v += __shfl_xor(v, off, 64);
  return v;
}
DEV float blockSum(float v, float* sred){
  v = waveSum(v);
  __syncthreads();
  if ((threadIdx.x & 63)==0) sred[threadIdx.x>>6] = v;
  __syncthreads();
  return sred[0]+sred[1]+sred[2]+sred[3];
}

// ---- dtype detection: block j probes float input j; bits 8..14 of first 128 words ----
__global__ __launch_bounds__(128) void k_detect(
    const u32* p0, const u32* p1, const u32* p2, const u32* p3,
    const u32* p4, const u32* p5, const u32* p6, const u32* p7,
    const u32* p8, const u32* p9, const u32* p10, int* flags)
{
  const u32* p = p0;
  switch (blockIdx.x){
    case 0: p=p0; break; case 1: p=p1; break; case 2: p=p2; break; case 3: p=p3; break;
    case 4: p=p4; break; case 5: p=p5; break; case 6: p=p6; break; case 7: p=p7; break;
    case 8: p=p8; break; case 9: p=p9; break; case 10: p=p10; break;
  }
  int t = threadIdx.x;
  u32 w = p[t];
  u32 e = (w>>8)&0x7Fu;
  int in = (e>=0x60u && e<=0x7Cu) ? 1 : 0;
  unsigned long long m = __ballot(in);
  __shared__ int cnt2[2];
  if ((t&63)==0) cnt2[t>>6] = __popcll(m);
  __syncthreads();
  if (t==0) flags[blockIdx.x] = ((cnt2[0]+cnt2[1]) > 96) ? 0 : 1; // 0 = bf16, 1 = f32
}

// flags index: 0=emb 1=pos 2=dis 3=target 4=pi 5=M 6=q 7=r 8=sc1w 9=sc1b 10=sc2w

// ---- fused: rnorm[v] = 1/max(||emb[v]||,eps) AND (f32 case) split emb -> hi/lo bf16 ----
// one wave per row, 4 rows per block
__global__ __launch_bounds__(256) void k_prep(const void* __restrict__ emb,
    float* __restrict__ rnorm, u16* __restrict__ ehi, u16* __restrict__ elo,
    const int* __restrict__ flags)
{
  int isf32 = flags[0];
  int v = blockIdx.x*4 + (threadIdx.x>>6);
  int lane = threadIdx.x & 63;
  size_t o = (size_t)v*D_ + lane*4;
  if (isf32){
    float4 q = *(const float4*)((const float*)emb + o);
    float ss = waveSum(q.x*q.x+q.y*q.y+q.z*q.z+q.w*q.w);
    if (lane==0) rnorm[v] = 1.0f/fmaxf(sqrtf(ss), 1e-12f);
    ushort4 h, l;
    h.x = f2bf(q.x); l.x = f2bf(q.x - bf2f(h.x));
    h.y = f2bf(q.y); l.y = f2bf(q.y - bf2f(h.y));
    h.z = f2bf(q.z); l.z = f2bf(q.z - bf2f(h.z));
    h.w = f2bf(q.w); l.w = f2bf(q.w - bf2f(h.w));
    *(ushort4*)(ehi+o) = h;
    *(ushort4*)(elo+o) = l;
  } else {
    uint2 p = *(const uint2*)((const u16*)emb + o);
    float a0=bflo(p.x), a1=bfhi(p.x), a2=bflo(p.y), a3=bfhi(p.y);
    float ss = waveSum(a0*a0+a1*a1+a2*a2+a3*a3);
    if (lane==0) rnorm[v] = 1.0f/fmaxf(sqrtf(ss), 1e-12f);
  }
}

// ---- GAT edge scores : one wave per edge ----
__global__ __launch_bounds__(256) void k_edge(
    const void* __restrict__ emb, const void* __restrict__ dis_emb,
    const void* __restrict__ pi_w, const void* __restrict__ M_w,
    const int* __restrict__ iid, const float* __restrict__ rnorm,
    const int* __restrict__ src, const int* __restrict__ dst, const int* __restrict__ dis,
    float* __restrict__ e_edge, const int* __restrict__ flags)
{
  int f_emb = flags[0], f_dis = flags[2], f_pi = flags[4], f_M = flags[5];
  int e = blockIdx.x*4 + (threadIdx.x>>6);
  int lane = threadIdx.x & 63;
  int s = src[e], d = dst[e], di = dis[e];
  int is = iid[s], idd = iid[d];
  float rs = rnorm[is], rd = rnorm[idd];
  int k0 = lane*4;
  float d1 = 0.f, d2 = 0.f;
  #pragma unroll
  for (int j=0;j<4;++j){
    int k = k0 + j;
    float hs = ldf(emb, (size_t)is*D_ + k, f_emb) * rs;
    float hd = ldf(emb, (size_t)idd*D_ + k, f_emb) * rd;
    float hx = ldf(dis_emb, (size_t)di*D_ + k, f_dis);
    float pr = hs*hd;
    d1 += pr * hx * ldf(pi_w, k, f_pi);
    d2 += pr * ldf(M_w, k, f_M) + hx * ldf(M_w, D_ + k, f_M);
  }
  d1 = waveSum(d1); d2 = waveSum(d2);
  if (lane==0){
    d1 = clampf(d1, -1e4f, 1e4f);
    d2 = clampf(d2, -60.f, 60.f);
    float gate = 1.0f/(1.0f+expf(-d2));
    e_edge[e] = d1*gate;
  }
}

// ---- CSR build by dst ----
__global__ __launch_bounds__(256) void k_count(const int* __restrict__ dst, int* __restrict__ cnt){
  int e = blockIdx.x*256+threadIdx.x;
  if (e<E_) atomicAdd(&cnt[dst[e]], 1);
}
__global__ __launch_bounds__(256) void k_scan(const int* __restrict__ cnt,
    int* __restrict__ offs, int* __restrict__ cursor){
  __shared__ int part[256];
  int t = threadIdx.x;
  const int CH = N_/256;
  int s = 0;
  for (int i=0;i<CH;++i) s += cnt[t*CH+i];
  part[t] = s; __syncthreads();
  if (t==0){
    int run=0;
    for (int i=0;i<256;++i){ int c=part[i]; part[i]=run; run+=c; }
    offs[N_] = run;
  }
  __syncthreads();
  int run = part[t];
  for (int i=0;i<CH;++i){ int idx=t*CH+i; offs[idx]=run; cursor[idx]=run; run+=cnt[idx]; }
}
__global__ __launch_bounds__(256) void k_scatter(const int* __restrict__ dst,
    int* __restrict__ cursor, int* __restrict__ elist){
  int e = blockIdx.x*256+threadIdx.x;
  if (e<E_){ int p = atomicAdd(&cursor[dst[e]],1); elist[p]=e; }
}

// ---- edge softmax + weighted aggregation : one block per dst node ----
__global__ __launch_bounds__(256) void k_gat(
    const void* __restrict__ emb, const int* __restrict__ iid,
    const float* __restrict__ rnorm, const float* __restrict__ e_edge,
    const int* __restrict__ offs, const int* __restrict__ elist,
    const int* __restrict__ src, float* __restrict__ hagg,
    const int* __restrict__ flags)
{
  int f_emb = flags[0];
  int n = blockIdx.x, t = threadIdx.x;
  int beg = offs[n], end = offs[n+1];
  float acc = 0.f;
  if (end > beg){
    float m = -3.0e38f;
    for (int j=beg;j<end;++j) m = fmaxf(m, e_edge[elist[j]]);
    float ssum = 0.f;
    for (int j=beg;j<end;++j) ssum += expf(e_edge[elist[j]] - m);
    float inv = 1.0f/fmaxf(ssum, 1e-30f);
    for (int j=beg;j<end;++j){
      int k = elist[j];
      int sk = src[k];
      int isk = iid[sk];
      float a = expf(e_edge[k]-m)*inv;
      acc += a * ldf(emb, (size_t)isk*D_ + t, f_emb) * rnorm[isk];
    }
  }
  hagg[(size_t)n*D_ + t] = acc;
}

// ---- f[b] = concat(h_t, last_feat) @ r_w : one block per session ----
__global__ __launch_bounds__(256) void k_f(
    const float* __restrict__ hagg, const void* __restrict__ target_emb,
    const void* __restrict__ r_w, const int* __restrict__ tid,
    const int* __restrict__ last_idx, float* __restrict__ fbuf,
    const int* __restrict__ flags)
{
  int f_t = flags[3], f_r = flags[7];
  __shared__ float scat[2*D_];
  int b = blockIdx.x, t = threadIdx.x;
  scat[t]     = ldf(target_emb, (size_t)tid[b]*D_ + t, f_t);
  scat[D_+t]  = hagg[(size_t)last_idx[b]*D_ + t];
  __syncthreads();
  float f = 0.f;
  for (int k=0;k<2*D_;++k) f += scat[k]*ldf(r_w, (size_t)k*D_ + t, f_r);
  fbuf[(size_t)b*D_ + t] = f;
}

// ---- coef : one WAVE per 8 agg edges; X rows in regs, broadcast via shfl ----
// xr[e][j] at lane L holds X_{n0+e}[L*8+j], X = [eft(256) | h_p(256)]
// lane owns t = lane*4 .. lane*4+3 output cols of eagg.
__global__ __launch_bounds__(64) void k_coef(
    const float* __restrict__ hagg, const void* __restrict__ pos_emb,
    const void* __restrict__ q_w, const float* __restrict__ fbuf,
    const int* __restrict__ pid, const int* __restrict__ agg_src,
    const int* __restrict__ agg_dst, float* __restrict__ coef,
    const int* __restrict__ flags)
{
  int f_p = flags[1], f_q = flags[6];
  int lane = threadIdx.x;
  int n0 = blockIdx.x*8;
  int t0 = lane*4;

  float xr[8][8];
  #pragma unroll
  for (int e=0;e<8;++e){
    int n = n0+e;
    if (lane < 32){
      const float* hp = hagg + (size_t)agg_src[n]*D_ + lane*8;
      float4 a = *(const float4*)hp;
      float4 b = *(const float4*)(hp+4);
      xr[e][0]=a.x; xr[e][1]=a.y; xr[e][2]=a.z; xr[e][3]=a.w;
      xr[e][4]=b.x; xr[e][5]=b.y; xr[e][6]=b.z; xr[e][7]=b.w;
    } else {
      size_t base = (size_t)pid[n]*D_ + (lane-32)*8;
      if (f_p){
        const float* pp = (const float*)pos_emb + base;
        float4 a = *(const float4*)pp;
        float4 b = *(const float4*)(pp+4);
        xr[e][0]=a.x; xr[e][1]=a.y; xr[e][2]=a.z; xr[e][3]=a.w;
        xr[e][4]=b.x; xr[e][5]=b.y; xr[e][6]=b.z; xr[e][7]=b.w;
      } else {
        const u16* pp = (const u16*)pos_emb + base;
        uint4 u = *(const uint4*)pp;
        xr[e][0]=bflo(u.x); xr[e][1]=bfhi(u.x); xr[e][2]=bflo(u.y); xr[e][3]=bfhi(u.y);
        xr[e][4]=bflo(u.z); xr[e][5]=bfhi(u.z); xr[e][6]=bflo(u.w); xr[e][7]=bfhi(u.w);
      }
    }
  }

  float y0[8], y1[8], y2[8], y3[8];
  #pragma unroll
  for (int e=0;e<8;++e){ y0[e]=0.f; y1[e]=0.f; y2[e]=0.f; y3[e]=0.f; }

  if (f_q){
    for (int kb=0; kb<64; ++kb){
      #pragma unroll
      for (int j=0;j<8;++j){
        int k = kb*8+j;
        float4 q = *(const float4*)((const float*)q_w + (size_t)k*D_ + t0);
        #pragma unroll
        for (int e=0;e<8;++e){
          float xk = __shfl(xr[e][j], kb, 64);
          y0[e] += xk*q.x; y1[e] += xk*q.y; y2[e] += xk*q.z; y3[e] += xk*q.w;
        }
      }
    }
  } else {
    for (int kb=0; kb<64; ++kb){
      #pragma unroll
      for (int j=0;j<8;++j){
        int k = kb*8+j;
        uint2 u = *(const uint2*)((const u16*)q_w + (size_t)k*D_ + t0);
        float qx=bflo(u.x), qy=bfhi(u.x), qz=bflo(u.y), qw=bfhi(u.y);
        #pragma unroll
        for (int e=0;e<8;++e){
          float xk = __shfl(xr[e][j], kb, 64);
          y0[e] += xk*qx; y1[e] += xk*qy; y2[e] += xk*qz; y3[e] += xk*qw;
        }
      }
    }
  }

  #pragma unroll
  for (int e=0;e<8;++e){
    int n = n0+e;
    int b = agg_dst[n];
    float4 f = *(const float4*)(fbuf + (size_t)b*D_ + t0);
    float s = tanhf(y0[e])*f.x + tanhf(y1[e])*f.y + tanhf(y2[e])*f.z + tanhf(y3[e])*f.w;
    s = waveSum(s);
    if (lane==0) coef[n] = clampf(s, -1e6f, 1e6f);
  }
}

// ---- sr (l2-normalized, emitted as split bf16 hi/lo) + logphi : one block per session ----
__global__ __launch_bounds__(256) void k_sr(
    const float* __restrict__ hagg, const float* __restrict__ coef,
    const void* __restrict__ sc1_w, const void* __restrict__ sc1_b,
    const void* __restrict__ sc2_w, const int* __restrict__ agg_src,
    u16* __restrict__ sr_hi, u16* __restrict__ sr_lo,
    float* __restrict__ logphi, const int* __restrict__ flags)
{
  int f_w1 = flags[8], f_b1 = flags[9], f_w2 = flags[10];
  __shared__ float ssr[D_];
  __shared__ float sred[4];
  int b = blockIdx.x, t = threadIdx.x;
  float srv = 0.f;
  for (int g=0; g<S_; ++g){
    int n = b*S_ + g;
    srv += hagg[(size_t)agg_src[n]*D_ + t] * coef[n];
  }
  float ss = blockSum(srv*srv, sred);
  float srn = srv / fmaxf(sqrtf(ss), 1e-12f);
  srn = clampf(srn, -2.f, 2.f);
  u16 h = f2bf(srn);
  sr_hi[(size_t)b*D_ + t] = h;
  sr_lo[(size_t)b*D_ + t] = f2bf(srn - bf2f(h));
  ssr[t] = srn;
  __syncthreads();
  float hid = ldf(sc1_b, t, f_b1);
  for (int k=0;k<D_;++k) hid += ssr[k]*ldf(sc1_w, (size_t)k*D_ + t, f_w1);
  hid = fmaxf(hid, 0.f);
  float z0 = blockSum(hid*ldf(sc2_w, t*2+0, f_w2), sred);
  float z1 = blockSum(hid*ldf(sc2_w, t*2+1, f_w2), sred);
  if (t==0){
    z0 = clampf(z0, -1e4f, 1e4f); z1 = clampf(z1, -1e4f, 1e4f);
    float mz = fmaxf(z0,z1);
    float lse = mz + logf(expf(z0-mz)+expf(z1-mz));
    logphi[2*b]   = z0 - lse;
    logphi[2*b+1] = z1 - lse;
  }
}

// ---- MFMA GEMM pass: x[b,v] = clamp(12 * (sr.emb_v) * rnorm[v]), Zall[b] += exp(x) ----
// No LDS, no barriers. Block = 4 waves sharing 16 b-rows; A (sr hi/lo, 16 rows)
// is register-resident: 16 x bf16x8 x 2 planes = 64 VGPRs/wave.
// Wave wv owns v-range [v0 + wv*64, +64) = 4 fragment-tiles of 16.
// mfma_f32_16x16x32_bf16: A row=lane&15(b), B col=lane&15(v), k=(lane>>4)*8+j;
// D: col(v)=lane&15, row(b)=(lane>>4)*4+reg.
// Grid (32 b-chunks, 391 v-chunks), x fastest: 32 consecutive blocks share the
// same 256 B-rows -> L2 reuse.
__global__ __launch_bounds__(256) void k_mm(
    const void* __restrict__ emb, const u16* __restrict__ emb_hi,
    const u16* __restrict__ emb_lo, const u16* __restrict__ sr_hi,
    const u16* __restrict__ sr_lo, const float* __restrict__ rnorm,
    float* __restrict__ Zall, void* __restrict__ outp,
    const int* __restrict__ flags)
{
  int isf32 = flags[0];
  int lane = threadIdx.x & 63;
  int wv   = threadIdx.x >> 6;
  int col  = lane & 15;   // fragment 16-dim index
  int kg   = lane >> 4;   // K-group 0..3
  int b0   = blockIdx.x*16;
  int v0   = blockIdx.y*256 + wv*64;

  // A fragments in registers: 16 b-rows x 8 k-steps, hi and lo planes
  bf16x8 ahi[8], alo[8];
  {
    const u16* rh = sr_hi + (size_t)(b0 + col)*D_ + kg*8;
    const u16* rl = sr_lo + (size_t)(b0 + col)*D_ + kg*8;
    #pragma unroll
    for (int ks=0;ks<8;++ks){
      ahi[ks] = *(const bf16x8*)(rh + ks*32);
      alo[ks] = *(const bf16x8*)(rl + ks*32);
    }
  }

  const u16* Bh = isf32 ? emb_hi : (const u16*)emb;

  int vr_[4];
  #pragma unroll
  for (int vt=0;vt<4;++vt){
    int vrow = v0 + vt*16 + col;
    vr_[vt] = vrow < V_ ? vrow : V_-1;
  }

  f32x4 acc[4];
  #pragma unroll
  for (int vt=0;vt<4;++vt) acc[vt] = (f32x4){0.f,0.f,0.f,0.f};

  if (isf32){
    #pragma unroll
    for (int vt=0; vt<4; ++vt){
      const u16* bp = Bh     + (size_t)vr_[vt]*D_ + kg*8;
      const u16* lp = emb_lo + (size_t)vr_[vt]*D_ + kg*8;
      #pragma unroll
      for (int ks=0; ks<8; ++ks){
        bf16x8 bh = *(const bf16x8*)(bp + ks*32);
        bf16x8 bl = *(const bf16x8*)(lp + ks*32);
        acc[vt] = __builtin_amdgcn_mfma_f32_16x16x32_bf16(ahi[ks], bh, acc[vt], 0,0,0);
        acc[vt] = __builtin_amdgcn_mfma_f32_16x16x32_bf16(alo[ks], bh, acc[vt], 0,0,0);
        acc[vt] = __builtin_amdgcn_mfma_f32_16x16x32_bf16(ahi[ks], bl, acc[vt], 0,0,0);
      }
    }
  } else {
    #pragma unroll
    for (int vt=0; vt<4; ++vt){
      const u16* bp = Bh + (size_t)vr_[vt]*D_ + kg*8;
      #pragma unroll
      for (int ks=0; ks<8; ++ks){
        bf16x8 bh = *(const bf16x8*)(bp + ks*32);
        acc[vt] = __builtin_amdgcn_mfma_f32_16x16x32_bf16(ahi[ks], bh, acc[vt], 0,0,0);
        acc[vt] = __builtin_amdgcn_mfma_f32_16x16x32_bf16(alo[ks], bh, acc[vt], 0,0,0);
      }
    }
  }

  // epilogue: scale, clamp, exp-accumulate, store
  float zs[4] = {0.f, 0.f, 0.f, 0.f};
  #pragma unroll
  for (int vt=0; vt<4; ++vt){
    int vrow = v0 + vt*16 + col;
    bool ok = vrow < V_;
    float rv = rnorm[vr_[vt]] * SCALE_;
    #pragma unroll
    for (int r=0;r<4;++r){
      float x = clampf(acc[vt][r]*rv, -40.f, 40.f);
      if (ok){
        zs[r] += expf(x);
        int b = b0 + kg*4 + r;
        stout(outp, (size_t)b*V_ + vrow, x, isf32);
      }
    }
  }
  // reduce zs across the 16 col-lanes (same kg), then one atomic per b
  #pragma unroll
  for (int r=0;r<4;++r){
    float z = zs[r];
    z += __shfl_xor(z, 1, 64);
    z += __shfl_xor(z, 2, 64);
    z += __shfl_xor(z, 4, 64);
    z += __shfl_xor(z, 8, 64);
    if (col==0) atomicAdd(&Zall[b0 + kg*4 + r], z);
  }
}

// ---- save logits at masked positions (before k_out clobbers them) ----
__global__ __launch_bounds__(256) void k_pre(const int* __restrict__ iid,
    const int* __restrict__ agg_dst, const void* __restrict__ outp,
    float* __restrict__ xsave, const int* __restrict__ flags)
{
  int isf32 = flags[0];
  int n = blockIdx.x*256 + threadIdx.x;
  if (n < N_){
    int b = agg_dst[n];
    int v = iid[n];
    xsave[n] = rdout(outp, (size_t)b*V_ + v, isf32);
  }
}

// ---- Zin[b] = sum over UNIQUE masked v of exp(x) ----
__global__ __launch_bounds__(64) void k_zin(const int* __restrict__ iid,
    const float* __restrict__ xsave, float* __restrict__ Zin)
{
  __shared__ int ids[S_];
  int b = blockIdx.x, g = threadIdx.x;
  if (g < S_) ids[g] = iid[b*S_ + g];
  __syncthreads();
  float z = 0.f;
  if (g < S_){
    bool first = true;
    for (int h=0; h<g; ++h) if (ids[h]==ids[g]){ first=false; break; }
    if (first) z = expf(clampf(xsave[b*S_+g], -40.f, 40.f));
  }
  z = waveSum(z);
  if (g==0) Zin[b] = z;
}

__global__ __launch_bounds__(256) void k_fin(const float* __restrict__ logphi,
    const float* __restrict__ Zall, const float* __restrict__ Zin,
    float* __restrict__ cin, float* __restrict__ cex)
{
  int b = blockIdx.x*256+threadIdx.x;
  if (b < B_){
    float zin = Zin[b];
    float zex = Zall[b] - zin;
    cin[b] = clampf(logphi[2*b]   - logf(fmaxf(zin, 1e-30f)), -1e4f, 1e4f);
    cex[b] = clampf(logphi[2*b+1] - logf(fmaxf(zex, 1e-30f)), -1e4f, 1e4f);
  }
}

// ---- pass 2: out = x + cex for ALL positions (masked fixed up by k_patch) ----
__global__ __launch_bounds__(256) void k_out(const float* __restrict__ cex,
    void* __restrict__ outp, const int* __restrict__ flags)
{
  int isf32 = flags[0];
  int b = blockIdx.y;
  int v0 = (blockIdx.x*256 + threadIdx.x)*4;
  if (v0 >= V_) return;
  float ce = cex[b];
  if (isf32){
    float4* p = (float4*)((float*)outp + (size_t)b*V_ + v0);
    float4 x = *p;
    x.x = clampf(x.x+ce, -1e4f, 1e4f); x.y = clampf(x.y+ce, -1e4f, 1e4f);
    x.z = clampf(x.z+ce, -1e4f, 1e4f); x.w = clampf(x.w+ce, -1e4f, 1e4f);
    *p = x;
  } else {
    ushort4* p = (ushort4*)((u16*)outp + (size_t)b*V_ + v0);
    ushort4 lg = *p;
    lg.x = f2bf(clampf(bf2f(lg.x)+ce, -1e4f, 1e4f));
    lg.y = f2bf(clampf(bf2f(lg.y)+ce, -1e4f, 1e4f));
    lg.z = f2bf(clampf(bf2f(lg.z)+ce, -1e4f, 1e4f));
    lg.w = f2bf(clampf(bf2f(lg.w)+ce, -1e4f, 1e4f));
    *p = lg;
  }
}

// ---- fix up masked positions: out[b, iid[n]] = xsave[n] + cin[b] ----
__global__ __launch_bounds__(256) void k_patch(const int* __restrict__ iid,
    const int* __restrict__ agg_dst, const float* __restrict__ xsave,
    const float* __restrict__ cin, void* __restrict__ outp,
    const int* __restrict__ flags)
{
  int isf32 = flags[0];
  int n = blockIdx.x*256 + threadIdx.x;
  if (n < N_){
    int b = agg_dst[n];
    int v = iid[n];
    float val = clampf(xsave[n] + cin[b], -1e4f, 1e4f);
    stout(outp, (size_t)b*V_ + v, val, isf32);
  }
}

extern "C" void kernel_launch(void* const* d_in, const int* in_sizes, int n_in,
                              void* d_out, int out_size, void* d_ws, size_t ws_size,
                              hipStream_t stream)
{
  (void)in_sizes; (void)n_in; (void)out_size; (void)ws_size;
  const int* iid      = (const int*)d_in[0];
  const int* src      = (const int*)d_in[1];
  const int* dst      = (const int*)d_in[2];
  const int* dis      = (const int*)d_in[3];
  const int* pid      = (const int*)d_in[4];
  const int* agg_src  = (const int*)d_in[5];
  const int* agg_dst  = (const int*)d_in[6];
  const int* tid      = (const int*)d_in[7];
  const int* last_idx = (const int*)d_in[8];
  const void* emb        = d_in[9];
  const void* pos_emb    = d_in[10];
  const void* dis_emb    = d_in[11];
  const void* target_emb = d_in[12];
  const void* pi_w  = d_in[13];
  const void* M_w   = d_in[14];
  const void* q_w   = d_in[15];
  const void* r_w   = d_in[16];
  const void* sc1_w = d_in[17];
  const void* sc1_b = d_in[18];
  const void* sc2_w = d_in[19];

  char* w = (char*)d_ws;
  size_t off = 0;
  auto alloc = [&](size_t bytes)->char*{
    char* p = w + off;
    off = (off + bytes + 255) & ~(size_t)255;
    return p;
  };
  // total ws use: ~116 MB (emb hi/lo planes dominate)
  int*   flags  = (int*)alloc(16*4);
  float* rnorm  = (float*)alloc((size_t)V_*4);        // 0.40 MB
  float* hagg   = (float*)alloc((size_t)N_*D_*4);     // 10.49 MB
  float* e_edge = (float*)alloc((size_t)E_*4);        // 0.33 MB
  int*   cnt    = (int*)alloc((size_t)N_*4);
  int*   offs   = (int*)alloc((size_t)(N_+1)*4);
  int*   cursor = (int*)alloc((size_t)N_*4);
  int*   elist  = (int*)alloc((size_t)E_*4);          // 0.33 MB
  float* fbuf   = (float*)alloc((size_t)B_*D_*4);     // 0.52 MB
  float* coef   = (float*)alloc((size_t)N_*4);
  u16*   sr_hi  = (u16*)alloc((size_t)B_*D_*2);       // 0.26 MB
  u16*   sr_lo  = (u16*)alloc((size_t)B_*D_*2);       // 0.26 MB
  float* logphi = (float*)alloc((size_t)2*B_*4);
  float* Zall   = (float*)alloc((size_t)B_*4);
  float* Zin    = (float*)alloc((size_t)B_*4);
  float* cin    = (float*)alloc((size_t)B_*4);
  float* cex    = (float*)alloc((size_t)B_*4);
  float* xsave  = (float*)alloc((size_t)N_*4);
  u16*   emb_hi = (u16*)alloc((size_t)V_*D_*2);       // 51.2 MB
  u16*   emb_lo = (u16*)alloc((size_t)V_*D_*2);       // 51.2 MB

  hipMemsetAsync(cnt, 0, (size_t)N_*4, stream);
  hipMemsetAsync(Zall, 0, (size_t)B_*4, stream);

  k_detect <<<11, 128, 0, stream>>>((const u32*)emb, (const u32*)pos_emb,
             (const u32*)dis_emb, (const u32*)target_emb, (const u32*)pi_w,
             (const u32*)M_w, (const u32*)q_w, (const u32*)r_w,
             (const u32*)sc1_w, (const u32*)sc1_b, (const u32*)sc2_w, flags);
  k_prep   <<<V_/4, 256, 0, stream>>>(emb, rnorm, emb_hi, emb_lo, flags);
  k_edge   <<<E_/4, 256, 0, stream>>>(emb, dis_emb, pi_w, M_w, iid, rnorm,
                                      src, dst, dis, e_edge, flags);
  k_count  <<<E_/256, 256, 0, stream>>>(dst, cnt);
  k_scan   <<<1, 256, 0, stream>>>(cnt, offs, cursor);
  k_scatter<<<E_/256, 256, 0, stream>>>(dst, cursor, elist);
  k_gat    <<<N_, 256, 0, stream>>>(emb, iid, rnorm, e_edge, offs, elist, src, hagg, flags);
  k_f      <<<B_, 256, 0, stream>>>(hagg, target_emb, r_w, tid, last_idx, fbuf, flags);
  k_coef   <<<N_/8, 64, 0, stream>>>(hagg, pos_emb, q_w, fbuf, pid, agg_src, agg_dst, coef, flags);
  k_sr     <<<B_, 256, 0, stream>>>(hagg, coef, sc1_w, sc1_b, sc2_w, agg_src,
                                    sr_hi, sr_lo, logphi, flags);
  k_mm     <<<dim3(32, 391), 256, 0, stream>>>(emb, emb_hi, emb_lo, sr_hi, sr_lo,
                                               rnorm, Zall, d_out, flags);
  k_pre    <<<(N_+255)/256, 256, 0, stream>>>(iid, agg_dst, d_out, xsave, flags);
  k_zin    <<<B_, 64, 0, stream>>>(iid, xsave, Zin);
  k_fin    <<<(B_+255)/256, 256, 0, stream>>>(logphi, Zall, Zin, cin, cex);
  k_out    <<<dim3((V_/4+255)/256, B_), 256, 0, stream>>>(cex, d_out, flags);
  k_patch  <<<(N_+255)/256, 256, 0, stream>>>(iid, agg_dst, xsave, cin, d_out, flags);
}

// Round 6
// 1014.954 us; speedup vs baseline: 1.2943x; 1.2943x over previous
//
#include <hip/hip_runtime.h>

typedef unsigned short u16;
typedef unsigned int u32;

constexpr int N_ = 10240, E_ = 81920, B_ = 512, S_ = 20, V_ = 100000, D_ = 256;
constexpr float SCALE_ = 12.0f;

#define DEV static __device__ __forceinline__

typedef __attribute__((ext_vector_type(8))) short bf16x8;
typedef __attribute__((ext_vector_type(4))) float f32x4;
typedef __attribute__((ext_vector_type(4))) u16 u16x4;

DEV float bf2f(u16 u){ union{u32 i; float f;} c; c.i = ((u32)u)<<16; return c.f; }
DEV float bflo(u32 u){ union{u32 i; float f;} c; c.i = u<<16; return c.f; }
DEV float bfhi(u32 u){ union{u32 i; float f;} c; c.i = u & 0xffff0000u; return c.f; }
DEV u16 f2bf(float f){ union{float f; u32 i;} c; c.f=f; u32 i=c.i; i += 0x7fffu + ((i>>16)&1u); return (u16)(i>>16); }
DEV float clampf(float x, float lo, float hi){ return fminf(fmaxf(x, lo), hi); } // NaN -> lo

// dtype-dispatched scalar load of float input
DEV float ldf(const void* p, size_t idx, int isf32){
  return isf32 ? ((const float*)p)[idx] : bf2f(((const u16*)p)[idx]);
}
DEV float rdout(const void* p, size_t idx, int isf32){
  return isf32 ? ((const float*)p)[idx] : bf2f(((const u16*)p)[idx]);
}
DEV void stout(void* p, size_t idx, float v, int isf32){
  if (isf32) ((float*)p)[idx] = v; else ((u16*)p)[idx] = f2bf(v);
}

DEV float waveSum(float v){
  #pragma unroll
  for (int off=32; off>0; off>>=1) v += __shfl_xor(v, off, 64);
  return v;
}
DEV float blockSum(float v, float* sred){
  v = waveSum(v);
  __syncthreads();
  if ((threadIdx.x & 63)==0) sred[threadIdx.x>>6] = v;
  __syncthreads();
  return sred[0]+sred[1]+sred[2]+sred[3];
}

// ---- dtype detection: block j probes float input j; bits 8..14 of first 128 words ----
__global__ __launch_bounds__(128) void k_detect(
    const u32* p0, const u32* p1, const u32* p2, const u32* p3,
    const u32* p4, const u32* p5, const u32* p6, const u32* p7,
    const u32* p8, const u32* p9, const u32* p10, int* flags)
{
  const u32* p = p0;
  switch (blockIdx.x){
    case 0: p=p0; break; case 1: p=p1; break; case 2: p=p2; break; case 3: p=p3; break;
    case 4: p=p4; break; case 5: p=p5; break; case 6: p=p6; break; case 7: p=p7; break;
    case 8: p=p8; break; case 9: p=p9; break; case 10: p=p10; break;
  }
  int t = threadIdx.x;
  u32 w = p[t];
  u32 e = (w>>8)&0x7Fu;
  int in = (e>=0x60u && e<=0x7Cu) ? 1 : 0;
  unsigned long long m = __ballot(in);
  __shared__ int cnt2[2];
  if ((t&63)==0) cnt2[t>>6] = __popcll(m);
  __syncthreads();
  if (t==0) flags[blockIdx.x] = ((cnt2[0]+cnt2[1]) > 96) ? 0 : 1; // 0 = bf16, 1 = f32
}

// flags index: 0=emb 1=pos 2=dis 3=target 4=pi 5=M 6=q 7=r 8=sc1w 9=sc1b 10=sc2w

// ---- fused: rnorm[v] = 1/max(||emb[v]||,eps) AND (f32 case) split emb -> hi/lo bf16 ----
// one wave per row, 4 rows per block
__global__ __launch_bounds__(256) void k_prep(const void* __restrict__ emb,
    float* __restrict__ rnorm, u16* __restrict__ ehi, u16* __restrict__ elo,
    const int* __restrict__ flags)
{
  int isf32 = flags[0];
  int v = blockIdx.x*4 + (threadIdx.x>>6);
  int lane = threadIdx.x & 63;
  size_t o = (size_t)v*D_ + lane*4;
  if (isf32){
    float4 q = *(const float4*)((const float*)emb + o);
    float ss = waveSum(q.x*q.x+q.y*q.y+q.z*q.z+q.w*q.w);
    if (lane==0) rnorm[v] = 1.0f/fmaxf(sqrtf(ss), 1e-12f);
    ushort4 h, l;
    h.x = f2bf(q.x); l.x = f2bf(q.x - bf2f(h.x));
    h.y = f2bf(q.y); l.y = f2bf(q.y - bf2f(h.y));
    h.z = f2bf(q.z); l.z = f2bf(q.z - bf2f(h.z));
    h.w = f2bf(q.w); l.w = f2bf(q.w - bf2f(h.w));
    *(ushort4*)(ehi+o) = h;
    *(ushort4*)(elo+o) = l;
  } else {
    uint2 p = *(const uint2*)((const u16*)emb + o);
    float a0=bflo(p.x), a1=bfhi(p.x), a2=bflo(p.y), a3=bfhi(p.y);
    float ss = waveSum(a0*a0+a1*a1+a2*a2+a3*a3);
    if (lane==0) rnorm[v] = 1.0f/fmaxf(sqrtf(ss), 1e-12f);
  }
}

// ---- GAT edge scores : one wave per edge ----
__global__ __launch_bounds__(256) void k_edge(
    const void* __restrict__ emb, const void* __restrict__ dis_emb,
    const void* __restrict__ pi_w, const void* __restrict__ M_w,
    const int* __restrict__ iid, const float* __restrict__ rnorm,
    const int* __restrict__ src, const int* __restrict__ dst, const int* __restrict__ dis,
    float* __restrict__ e_edge, const int* __restrict__ flags)
{
  int f_emb = flags[0], f_dis = flags[2], f_pi = flags[4], f_M = flags[5];
  int e = blockIdx.x*4 + (threadIdx.x>>6);
  int lane = threadIdx.x & 63;
  int s = src[e], d = dst[e], di = dis[e];
  int is = iid[s], idd = iid[d];
  float rs = rnorm[is], rd = rnorm[idd];
  int k0 = lane*4;
  float d1 = 0.f, d2 = 0.f;
  #pragma unroll
  for (int j=0;j<4;++j){
    int k = k0 + j;
    float hs = ldf(emb, (size_t)is*D_ + k, f_emb) * rs;
    float hd = ldf(emb, (size_t)idd*D_ + k, f_emb) * rd;
    float hx = ldf(dis_emb, (size_t)di*D_ + k, f_dis);
    float pr = hs*hd;
    d1 += pr * hx * ldf(pi_w, k, f_pi);
    d2 += pr * ldf(M_w, k, f_M) + hx * ldf(M_w, D_ + k, f_M);
  }
  d1 = waveSum(d1); d2 = waveSum(d2);
  if (lane==0){
    d1 = clampf(d1, -1e4f, 1e4f);
    d2 = clampf(d2, -60.f, 60.f);
    float gate = 1.0f/(1.0f+expf(-d2));
    e_edge[e] = d1*gate;
  }
}

// ---- CSR build by dst ----
__global__ __launch_bounds__(256) void k_count(const int* __restrict__ dst, int* __restrict__ cnt){
  int e = blockIdx.x*256+threadIdx.x;
  if (e<E_) atomicAdd(&cnt[dst[e]], 1);
}
__global__ __launch_bounds__(256) void k_scan(const int* __restrict__ cnt,
    int* __restrict__ offs, int* __restrict__ cursor){
  __shared__ int part[256];
  int t = threadIdx.x;
  const int CH = N_/256;
  int s = 0;
  for (int i=0;i<CH;++i) s += cnt[t*CH+i];
  part[t] = s; __syncthreads();
  if (t==0){
    int run=0;
    for (int i=0;i<256;++i){ int c=part[i]; part[i]=run; run+=c; }
    offs[N_] = run;
  }
  __syncthreads();
  int run = part[t];
  for (int i=0;i<CH;++i){ int idx=t*CH+i; offs[idx]=run; cursor[idx]=run; run+=cnt[idx]; }
}
__global__ __launch_bounds__(256) void k_scatter(const int* __restrict__ dst,
    int* __restrict__ cursor, int* __restrict__ elist){
  int e = blockIdx.x*256+threadIdx.x;
  if (e<E_){ int p = atomicAdd(&cursor[dst[e]],1); elist[p]=e; }
}

// ---- edge softmax + weighted aggregation : one block per dst node ----
__global__ __launch_bounds__(256) void k_gat(
    const void* __restrict__ emb, const int* __restrict__ iid,
    const float* __restrict__ rnorm, const float* __restrict__ e_edge,
    const int* __restrict__ offs, const int* __restrict__ elist,
    const int* __restrict__ src, float* __restrict__ hagg,
    const int* __restrict__ flags)
{
  int f_emb = flags[0];
  int n = blockIdx.x, t = threadIdx.x;
  int beg = offs[n], end = offs[n+1];
  float acc = 0.f;
  if (end > beg){
    float m = -3.0e38f;
    for (int j=beg;j<end;++j) m = fmaxf(m, e_edge[elist[j]]);
    float ssum = 0.f;
    for (int j=beg;j<end;++j) ssum += expf(e_edge[elist[j]] - m);
    float inv = 1.0f/fmaxf(ssum, 1e-30f);
    for (int j=beg;j<end;++j){
      int k = elist[j];
      int sk = src[k];
      int isk = iid[sk];
      float a = expf(e_edge[k]-m)*inv;
      acc += a * ldf(emb, (size_t)isk*D_ + t, f_emb) * rnorm[isk];
    }
  }
  hagg[(size_t)n*D_ + t] = acc;
}

// ---- f[b] = concat(h_t, last_feat) @ r_w : one block per session ----
__global__ __launch_bounds__(256) void k_f(
    const float* __restrict__ hagg, const void* __restrict__ target_emb,
    const void* __restrict__ r_w, const int* __restrict__ tid,
    const int* __restrict__ last_idx, float* __restrict__ fbuf,
    const int* __restrict__ flags)
{
  int f_t = flags[3], f_r = flags[7];
  __shared__ float scat[2*D_];
  int b = blockIdx.x, t = threadIdx.x;
  scat[t]     = ldf(target_emb, (size_t)tid[b]*D_ + t, f_t);
  scat[D_+t]  = hagg[(size_t)last_idx[b]*D_ + t];
  __syncthreads();
  float f = 0.f;
  for (int k=0;k<2*D_;++k) f += scat[k]*ldf(r_w, (size_t)k*D_ + t, f_r);
  fbuf[(size_t)b*D_ + t] = f;
}

// ---- coef : one WAVE per 8 agg edges; X rows in regs, broadcast via shfl ----
// xr[e][j] at lane L holds X_{n0+e}[L*8+j], X = [eft(256) | h_p(256)]
// lane owns t = lane*4 .. lane*4+3 output cols of eagg.
__global__ __launch_bounds__(64) void k_coef(
    const float* __restrict__ hagg, const void* __restrict__ pos_emb,
    const void* __restrict__ q_w, const float* __restrict__ fbuf,
    const int* __restrict__ pid, const int* __restrict__ agg_src,
    const int* __restrict__ agg_dst, float* __restrict__ coef,
    const int* __restrict__ flags)
{
  int f_p = flags[1], f_q = flags[6];
  int lane = threadIdx.x;
  int n0 = blockIdx.x*8;
  int t0 = lane*4;

  float xr[8][8];
  #pragma unroll
  for (int e=0;e<8;++e){
    int n = n0+e;
    if (lane < 32){
      const float* hp = hagg + (size_t)agg_src[n]*D_ + lane*8;
      float4 a = *(const float4*)hp;
      float4 b = *(const float4*)(hp+4);
      xr[e][0]=a.x; xr[e][1]=a.y; xr[e][2]=a.z; xr[e][3]=a.w;
      xr[e][4]=b.x; xr[e][5]=b.y; xr[e][6]=b.z; xr[e][7]=b.w;
    } else {
      size_t base = (size_t)pid[n]*D_ + (lane-32)*8;
      if (f_p){
        const float* pp = (const float*)pos_emb + base;
        float4 a = *(const float4*)pp;
        float4 b = *(const float4*)(pp+4);
        xr[e][0]=a.x; xr[e][1]=a.y; xr[e][2]=a.z; xr[e][3]=a.w;
        xr[e][4]=b.x; xr[e][5]=b.y; xr[e][6]=b.z; xr[e][7]=b.w;
      } else {
        const u16* pp = (const u16*)pos_emb + base;
        uint4 u = *(const uint4*)pp;
        xr[e][0]=bflo(u.x); xr[e][1]=bfhi(u.x); xr[e][2]=bflo(u.y); xr[e][3]=bfhi(u.y);
        xr[e][4]=bflo(u.z); xr[e][5]=bfhi(u.z); xr[e][6]=bflo(u.w); xr[e][7]=bfhi(u.w);
      }
    }
  }

  float y0[8], y1[8], y2[8], y3[8];
  #pragma unroll
  for (int e=0;e<8;++e){ y0[e]=0.f; y1[e]=0.f; y2[e]=0.f; y3[e]=0.f; }

  if (f_q){
    for (int kb=0; kb<64; ++kb){
      #pragma unroll
      for (int j=0;j<8;++j){
        int k = kb*8+j;
        float4 q = *(const float4*)((const float*)q_w + (size_t)k*D_ + t0);
        #pragma unroll
        for (int e=0;e<8;++e){
          float xk = __shfl(xr[e][j], kb, 64);
          y0[e] += xk*q.x; y1[e] += xk*q.y; y2[e] += xk*q.z; y3[e] += xk*q.w;
        }
      }
    }
  } else {
    for (int kb=0; kb<64; ++kb){
      #pragma unroll
      for (int j=0;j<8;++j){
        int k = kb*8+j;
        uint2 u = *(const uint2*)((const u16*)q_w + (size_t)k*D_ + t0);
        float qx=bflo(u.x), qy=bfhi(u.x), qz=bflo(u.y), qw=bfhi(u.y);
        #pragma unroll
        for (int e=0;e<8;++e){
          float xk = __shfl(xr[e][j], kb, 64);
          y0[e] += xk*qx; y1[e] += xk*qy; y2[e] += xk*qz; y3[e] += xk*qw;
        }
      }
    }
  }

  #pragma unroll
  for (int e=0;e<8;++e){
    int n = n0+e;
    int b = agg_dst[n];
    float4 f = *(const float4*)(fbuf + (size_t)b*D_ + t0);
    float s = tanhf(y0[e])*f.x + tanhf(y1[e])*f.y + tanhf(y2[e])*f.z + tanhf(y3[e])*f.w;
    s = waveSum(s);
    if (lane==0) coef[n] = clampf(s, -1e6f, 1e6f);
  }
}

// ---- sr (l2-normalized, emitted as split bf16 hi/lo) + logphi : one block per session ----
__global__ __launch_bounds__(256) void k_sr(
    const float* __restrict__ hagg, const float* __restrict__ coef,
    const void* __restrict__ sc1_w, const void* __restrict__ sc1_b,
    const void* __restrict__ sc2_w, const int* __restrict__ agg_src,
    u16* __restrict__ sr_hi, u16* __restrict__ sr_lo,
    float* __restrict__ logphi, const int* __restrict__ flags)
{
  int f_w1 = flags[8], f_b1 = flags[9], f_w2 = flags[10];
  __shared__ float ssr[D_];
  __shared__ float sred[4];
  int b = blockIdx.x, t = threadIdx.x;
  float srv = 0.f;
  for (int g=0; g<S_; ++g){
    int n = b*S_ + g;
    srv += hagg[(size_t)agg_src[n]*D_ + t] * coef[n];
  }
  float ss = blockSum(srv*srv, sred);
  float srn = srv / fmaxf(sqrtf(ss), 1e-12f);
  srn = clampf(srn, -2.f, 2.f);
  u16 h = f2bf(srn);
  sr_hi[(size_t)b*D_ + t] = h;
  sr_lo[(size_t)b*D_ + t] = f2bf(srn - bf2f(h));
  ssr[t] = srn;
  __syncthreads();
  float hid = ldf(sc1_b, t, f_b1);
  for (int k=0;k<D_;++k) hid += ssr[k]*ldf(sc1_w, (size_t)k*D_ + t, f_w1);
  hid = fmaxf(hid, 0.f);
  float z0 = blockSum(hid*ldf(sc2_w, t*2+0, f_w2), sred);
  float z1 = blockSum(hid*ldf(sc2_w, t*2+1, f_w2), sred);
  if (t==0){
    z0 = clampf(z0, -1e4f, 1e4f); z1 = clampf(z1, -1e4f, 1e4f);
    float mz = fmaxf(z0,z1);
    float lse = mz + logf(expf(z0-mz)+expf(z1-mz));
    logphi[2*b]   = z0 - lse;
    logphi[2*b+1] = z1 - lse;
  }
}

// ---- MFMA GEMM pass: x[b,v] = clamp(12 * (sr.emb_v) * rnorm[v]), Zall[b] += exp(x) ----
// ks-OUTER structure: only the current ks's A-fragments are live (16 VGPR),
// so the irreducible register set is acc(64)+A(16)+B(~16) ~= 110 VGPR and the
// compiler cannot profitably rematerialize A (it is consumed immediately).
// Block = 4 waves x 32 b-rows; wave owns 128 v (8 fragment tiles).
// mfma_f32_16x16x32_bf16: A row=lane&15(b), B col=lane&15(v), k=(lane>>4)*8+j;
// D: col(v)=lane&15, row(b)=(lane>>4)*4+reg.
// Non-temporal stores keep the 205MB logit stream out of L2/L3 so B stays cached.
// Grid (16 b-chunks, 196 v-chunks), x fastest: blocks sharing B are adjacent.
__global__ __launch_bounds__(256, 2) void k_mm(
    const void* __restrict__ emb, const u16* __restrict__ emb_hi,
    const u16* __restrict__ emb_lo, const u16* __restrict__ sr_hi,
    const u16* __restrict__ sr_lo, const float* __restrict__ rnorm,
    float* __restrict__ Zall, void* __restrict__ outp,
    const int* __restrict__ flags)
{
  int isf32 = flags[0];
  int lane = threadIdx.x & 63;
  int wv   = threadIdx.x >> 6;
  int col  = lane & 15;   // fragment 16-dim index
  int kg   = lane >> 4;   // K-group 0..3
  int b0   = blockIdx.x*32;
  int v0   = blockIdx.y*512 + wv*128;

  int vr_[8];
  #pragma unroll
  for (int vt=0;vt<8;++vt){
    int vrow = v0 + vt*16 + col;
    vr_[vt] = vrow < V_ ? vrow : V_-1;
  }

  const u16* Bh  = isf32 ? emb_hi : (const u16*)emb;
  const u16* arh = sr_hi + (size_t)(b0 + col)*D_ + kg*8;
  const u16* arl = sr_lo + (size_t)(b0 + col)*D_ + kg*8;

  f32x4 acc[8][2];
  #pragma unroll
  for (int vt=0;vt<8;++vt){
    acc[vt][0] = (f32x4){0.f,0.f,0.f,0.f};
    acc[vt][1] = (f32x4){0.f,0.f,0.f,0.f};
  }

  if (isf32){
    #pragma unroll 1
    for (int ks=0; ks<8; ++ks){
      int ko = ks*32;
      bf16x8 ah0 = *(const bf16x8*)(arh + ko);
      bf16x8 ah1 = *(const bf16x8*)(arh + 16*D_ + ko);
      bf16x8 al0 = *(const bf16x8*)(arl + ko);
      bf16x8 al1 = *(const bf16x8*)(arl + 16*D_ + ko);
      #pragma unroll
      for (int vt=0; vt<8; ++vt){
        size_t bo = (size_t)vr_[vt]*D_ + ko + kg*8;
        bf16x8 bh = *(const bf16x8*)(Bh + bo);
        bf16x8 bl = *(const bf16x8*)(emb_lo + bo);
        acc[vt][0] = __builtin_amdgcn_mfma_f32_16x16x32_bf16(ah0, bh, acc[vt][0], 0,0,0);
        acc[vt][1] = __builtin_amdgcn_mfma_f32_16x16x32_bf16(ah1, bh, acc[vt][1], 0,0,0);
        acc[vt][0] = __builtin_amdgcn_mfma_f32_16x16x32_bf16(al0, bh, acc[vt][0], 0,0,0);
        acc[vt][1] = __builtin_amdgcn_mfma_f32_16x16x32_bf16(al1, bh, acc[vt][1], 0,0,0);
        acc[vt][0] = __builtin_amdgcn_mfma_f32_16x16x32_bf16(ah0, bl, acc[vt][0], 0,0,0);
        acc[vt][1] = __builtin_amdgcn_mfma_f32_16x16x32_bf16(ah1, bl, acc[vt][1], 0,0,0);
      }
    }
  } else {
    #pragma unroll 1
    for (int ks=0; ks<8; ++ks){
      int ko = ks*32;
      bf16x8 ah0 = *(const bf16x8*)(arh + ko);
      bf16x8 ah1 = *(const bf16x8*)(arh + 16*D_ + ko);
      bf16x8 al0 = *(const bf16x8*)(arl + ko);
      bf16x8 al1 = *(const bf16x8*)(arl + 16*D_ + ko);
      #pragma unroll
      for (int vt=0; vt<8; ++vt){
        size_t bo = (size_t)vr_[vt]*D_ + ko + kg*8;
        bf16x8 bh = *(const bf16x8*)(Bh + bo);
        acc[vt][0] = __builtin_amdgcn_mfma_f32_16x16x32_bf16(ah0, bh, acc[vt][0], 0,0,0);
        acc[vt][1] = __builtin_amdgcn_mfma_f32_16x16x32_bf16(ah1, bh, acc[vt][1], 0,0,0);
        acc[vt][0] = __builtin_amdgcn_mfma_f32_16x16x32_bf16(al0, bh, acc[vt][0], 0,0,0);
        acc[vt][1] = __builtin_amdgcn_mfma_f32_16x16x32_bf16(al1, bh, acc[vt][1], 0,0,0);
      }
    }
  }

  // epilogue: scale, clamp, exp-accumulate, non-temporal store
  float zs[2][4];
  #pragma unroll
  for (int m=0;m<2;++m){ zs[m][0]=0.f; zs[m][1]=0.f; zs[m][2]=0.f; zs[m][3]=0.f; }

  #pragma unroll
  for (int vt=0; vt<8; ++vt){
    int vrow = v0 + vt*16 + col;
    bool ok = vrow < V_;
    float rv = rnorm[vr_[vt]] * SCALE_;
    #pragma unroll
    for (int m=0;m<2;++m){
      #pragma unroll
      for (int r=0;r<4;++r){
        float x = clampf(acc[vt][m][r]*rv, -40.f, 40.f);
        if (ok){
          zs[m][r] += expf(x);
          int b = b0 + m*16 + kg*4 + r;
          if (isf32) __builtin_nontemporal_store(x, (float*)outp + (size_t)b*V_ + vrow);
          else       __builtin_nontemporal_store(f2bf(x), (u16*)outp + (size_t)b*V_ + vrow);
        }
      }
    }
  }
  // reduce zs across the 16 col-lanes (same kg), then one atomic per b
  #pragma unroll
  for (int m=0;m<2;++m){
    #pragma unroll
    for (int r=0;r<4;++r){
      float z = zs[m][r];
      z += __shfl_xor(z, 1, 64);
      z += __shfl_xor(z, 2, 64);
      z += __shfl_xor(z, 4, 64);
      z += __shfl_xor(z, 8, 64);
      if (col==0) atomicAdd(&Zall[b0 + m*16 + kg*4 + r], z);
    }
  }
}

// ---- save logits at masked positions (before k_out clobbers them) ----
__global__ __launch_bounds__(256) void k_pre(const int* __restrict__ iid,
    const int* __restrict__ agg_dst, const void* __restrict__ outp,
    float* __restrict__ xsave, const int* __restrict__ flags)
{
  int isf32 = flags[0];
  int n = blockIdx.x*256 + threadIdx.x;
  if (n < N_){
    int b = agg_dst[n];
    int v = iid[n];
    xsave[n] = rdout(outp, (size_t)b*V_ + v, isf32);
  }
}

// ---- Zin[b] = sum over UNIQUE masked v of exp(x) ----
__global__ __launch_bounds__(64) void k_zin(const int* __restrict__ iid,
    const float* __restrict__ xsave, float* __restrict__ Zin)
{
  __shared__ int ids[S_];
  int b = blockIdx.x, g = threadIdx.x;
  if (g < S_) ids[g] = iid[b*S_ + g];
  __syncthreads();
  float z = 0.f;
  if (g < S_){
    bool first = true;
    for (int h=0; h<g; ++h) if (ids[h]==ids[g]){ first=false; break; }
    if (first) z = expf(clampf(xsave[b*S_+g], -40.f, 40.f));
  }
  z = waveSum(z);
  if (g==0) Zin[b] = z;
}

__global__ __launch_bounds__(256) void k_fin(const float* __restrict__ logphi,
    const float* __restrict__ Zall, const float* __restrict__ Zin,
    float* __restrict__ cin, float* __restrict__ cex)
{
  int b = blockIdx.x*256+threadIdx.x;
  if (b < B_){
    float zin = Zin[b];
    float zex = Zall[b] - zin;
    cin[b] = clampf(logphi[2*b]   - logf(fmaxf(zin, 1e-30f)), -1e4f, 1e4f);
    cex[b] = clampf(logphi[2*b+1] - logf(fmaxf(zex, 1e-30f)), -1e4f, 1e4f);
  }
}

// ---- pass 2: out = x + cex for ALL positions (masked fixed up by k_patch) ----
// non-temporal both ways (ext-vector types): pure stream, nothing re-reads it
__global__ __launch_bounds__(256) void k_out(const float* __restrict__ cex,
    void* __restrict__ outp, const int* __restrict__ flags)
{
  int isf32 = flags[0];
  int b = blockIdx.y;
  int v0 = (blockIdx.x*256 + threadIdx.x)*4;
  if (v0 >= V_) return;
  float ce = cex[b];
  if (isf32){
    float* p = (float*)outp + (size_t)b*V_ + v0;
    f32x4 x = __builtin_nontemporal_load((const f32x4*)p);
    x[0] = clampf(x[0]+ce, -1e4f, 1e4f); x[1] = clampf(x[1]+ce, -1e4f, 1e4f);
    x[2] = clampf(x[2]+ce, -1e4f, 1e4f); x[3] = clampf(x[3]+ce, -1e4f, 1e4f);
    __builtin_nontemporal_store(x, (f32x4*)p);
  } else {
    u16* p = (u16*)outp + (size_t)b*V_ + v0;
    u16x4 lg = __builtin_nontemporal_load((const u16x4*)p);
    lg[0] = f2bf(clampf(bf2f(lg[0])+ce, -1e4f, 1e4f));
    lg[1] = f2bf(clampf(bf2f(lg[1])+ce, -1e4f, 1e4f));
    lg[2] = f2bf(clampf(bf2f(lg[2])+ce, -1e4f, 1e4f));
    lg[3] = f2bf(clampf(bf2f(lg[3])+ce, -1e4f, 1e4f));
    __builtin_nontemporal_store(lg, (u16x4*)p);
  }
}

// ---- fix up masked positions: out[b, iid[n]] = xsave[n] + cin[b] ----
__global__ __launch_bounds__(256) void k_patch(const int* __restrict__ iid,
    const int* __restrict__ agg_dst, const float* __restrict__ xsave,
    const float* __restrict__ cin, void* __restrict__ outp,
    const int* __restrict__ flags)
{
  int isf32 = flags[0];
  int n = blockIdx.x*256 + threadIdx.x;
  if (n < N_){
    int b = agg_dst[n];
    int v = iid[n];
    float val = clampf(xsave[n] + cin[b], -1e4f, 1e4f);
    stout(outp, (size_t)b*V_ + v, val, isf32);
  }
}

extern "C" void kernel_launch(void* const* d_in, const int* in_sizes, int n_in,
                              void* d_out, int out_size, void* d_ws, size_t ws_size,
                              hipStream_t stream)
{
  (void)in_sizes; (void)n_in; (void)out_size; (void)ws_size;
  const int* iid      = (const int*)d_in[0];
  const int* src      = (const int*)d_in[1];
  const int* dst      = (const int*)d_in[2];
  const int* dis      = (const int*)d_in[3];
  const int* pid      = (const int*)d_in[4];
  const int* agg_src  = (const int*)d_in[5];
  const int* agg_dst  = (const int*)d_in[6];
  const int* tid      = (const int*)d_in[7];
  const int* last_idx = (const int*)d_in[8];
  const void* emb        = d_in[9];
  const void* pos_emb    = d_in[10];
  const void* dis_emb    = d_in[11];
  const void* target_emb = d_in[12];
  const void* pi_w  = d_in[13];
  const void* M_w   = d_in[14];
  const void* q_w   = d_in[15];
  const void* r_w   = d_in[16];
  const void* sc1_w = d_in[17];
  const void* sc1_b = d_in[18];
  const void* sc2_w = d_in[19];

  char* w = (char*)d_ws;
  size_t off = 0;
  auto alloc = [&](size_t bytes)->char*{
    char* p = w + off;
    off = (off + bytes + 255) & ~(size_t)255;
    return p;
  };
  // total ws use: ~116 MB (emb hi/lo planes dominate)
  int*   flags  = (int*)alloc(16*4);
  float* rnorm  = (float*)alloc((size_t)V_*4);        // 0.40 MB
  float* hagg   = (float*)alloc((size_t)N_*D_*4);     // 10.49 MB
  float* e_edge = (float*)alloc((size_t)E_*4);        // 0.33 MB
  int*   cnt    = (int*)alloc((size_t)N_*4);
  int*   offs   = (int*)alloc((size_t)(N_+1)*4);
  int*   cursor = (int*)alloc((size_t)N_*4);
  int*   elist  = (int*)alloc((size_t)E_*4);          // 0.33 MB
  float* fbuf   = (float*)alloc((size_t)B_*D_*4);     // 0.52 MB
  float* coef   = (float*)alloc((size_t)N_*4);
  u16*   sr_hi  = (u16*)alloc((size_t)B_*D_*2);       // 0.26 MB
  u16*   sr_lo  = (u16*)alloc((size_t)B_*D_*2);       // 0.26 MB
  float* logphi = (float*)alloc((size_t)2*B_*4);
  float* Zall   = (float*)alloc((size_t)B_*4);
  float* Zin    = (float*)alloc((size_t)B_*4);
  float* cin    = (float*)alloc((size_t)B_*4);
  float* cex    = (float*)alloc((size_t)B_*4);
  float* xsave  = (float*)alloc((size_t)N_*4);
  u16*   emb_hi = (u16*)alloc((size_t)V_*D_*2);       // 51.2 MB
  u16*   emb_lo = (u16*)alloc((size_t)V_*D_*2);       // 51.2 MB

  hipMemsetAsync(cnt, 0, (size_t)N_*4, stream);
  hipMemsetAsync(Zall, 0, (size_t)B_*4, stream);

  k_detect <<<11, 128, 0, stream>>>((const u32*)emb, (const u32*)pos_emb,
             (const u32*)dis_emb, (const u32*)target_emb, (const u32*)pi_w,
             (const u32*)M_w, (const u32*)q_w, (const u32*)r_w,
             (const u32*)sc1_w, (const u32*)sc1_b, (const u32*)sc2_w, flags);
  k_prep   <<<V_/4, 256, 0, stream>>>(emb, rnorm, emb_hi, emb_lo, flags);
  k_edge   <<<E_/4, 256, 0, stream>>>(emb, dis_emb, pi_w, M_w, iid, rnorm,
                                      src, dst, dis, e_edge, flags);
  k_count  <<<E_/256, 256, 0, stream>>>(dst, cnt);
  k_scan   <<<1, 256, 0, stream>>>(cnt, offs, cursor);
  k_scatter<<<E_/256, 256, 0, stream>>>(dst, cursor, elist);
  k_gat    <<<N_, 256, 0, stream>>>(emb, iid, rnorm, e_edge, offs, elist, src, hagg, flags);
  k_f      <<<B_, 256, 0, stream>>>(hagg, target_emb, r_w, tid, last_idx, fbuf, flags);
  k_coef   <<<N_/8, 64, 0, stream>>>(hagg, pos_emb, q_w, fbuf, pid, agg_src, agg_dst, coef, flags);
  k_sr     <<<B_, 256, 0, stream>>>(hagg, coef, sc1_w, sc1_b, sc2_w, agg_src,
                                    sr_hi, sr_lo, logphi, flags);
  k_mm     <<<dim3(16, 196), 256, 0, stream>>>(emb, emb_hi, emb_lo, sr_hi, sr_lo,
                                               rnorm, Zall, d_out, flags);
  k_pre    <<<(N_+255)/256, 256, 0, stream>>>(iid, agg_dst, d_out, xsave, flags);
  k_zin    <<<B_, 64, 0, stream>>>(iid, xsave, Zin);
  k_fin    <<<(B_+255)/256, 256, 0, stream>>>(logphi, Zall, Zin, cin, cex);
  k_out    <<<dim3((V_/4+255)/256, B_), 256, 0, stream>>>(cex, d_out, flags);
  k_patch  <<<(N_+255)/256, 256, 0, stream>>>(iid, agg_dst, xsave, cin, d_out, flags);
}

// Round 7
// 1006.358 us; speedup vs baseline: 1.3054x; 1.0085x over previous
//
#include <hip/hip_runtime.h>

typedef unsigned short u16;
typedef unsigned int u32;

constexpr int N_ = 10240, E_ = 81920, B_ = 512, S_ = 20, V_ = 100000, D_ = 256;
constexpr float SCALE_ = 12.0f;

#define DEV static __device__ __forceinline__

typedef __attribute__((ext_vector_type(8))) short bf16x8;
typedef __attribute__((ext_vector_type(4))) float f32x4;
typedef __attribute__((ext_vector_type(4))) u16 u16x4;

DEV float bf2f(u16 u){ union{u32 i; float f;} c; c.i = ((u32)u)<<16; return c.f; }
DEV float bflo(u32 u){ union{u32 i; float f;} c; c.i = u<<16; return c.f; }
DEV float bfhi(u32 u){ union{u32 i; float f;} c; c.i = u & 0xffff0000u; return c.f; }
DEV u16 f2bf(float f){ union{float f; u32 i;} c; c.f=f; u32 i=c.i; i += 0x7fffu + ((i>>16)&1u); return (u16)(i>>16); }
DEV float clampf(float x, float lo, float hi){ return fminf(fmaxf(x, lo), hi); } // NaN -> lo

// dtype-dispatched scalar load of float input
DEV float ldf(const void* p, size_t idx, int isf32){
  return isf32 ? ((const float*)p)[idx] : bf2f(((const u16*)p)[idx]);
}
DEV float rdout(const void* p, size_t idx, int isf32){
  return isf32 ? ((const float*)p)[idx] : bf2f(((const u16*)p)[idx]);
}
DEV void stout(void* p, size_t idx, float v, int isf32){
  if (isf32) ((float*)p)[idx] = v; else ((u16*)p)[idx] = f2bf(v);
}

DEV float waveSum(float v){
  #pragma unroll
  for (int off=32; off>0; off>>=1) v += __shfl_xor(v, off, 64);
  return v;
}
DEV float blockSum(float v, float* sred){
  v = waveSum(v);
  __syncthreads();
  if ((threadIdx.x & 63)==0) sred[threadIdx.x>>6] = v;
  __syncthreads();
  return sred[0]+sred[1]+sred[2]+sred[3];
}

// ---- dtype detection: block j probes float input j; bits 8..14 of first 128 words ----
__global__ __launch_bounds__(128) void k_detect(
    const u32* p0, const u32* p1, const u32* p2, const u32* p3,
    const u32* p4, const u32* p5, const u32* p6, const u32* p7,
    const u32* p8, const u32* p9, const u32* p10, int* flags)
{
  const u32* p = p0;
  switch (blockIdx.x){
    case 0: p=p0; break; case 1: p=p1; break; case 2: p=p2; break; case 3: p=p3; break;
    case 4: p=p4; break; case 5: p=p5; break; case 6: p=p6; break; case 7: p=p7; break;
    case 8: p=p8; break; case 9: p=p9; break; case 10: p=p10; break;
  }
  int t = threadIdx.x;
  u32 w = p[t];
  u32 e = (w>>8)&0x7Fu;
  int in = (e>=0x60u && e<=0x7Cu) ? 1 : 0;
  unsigned long long m = __ballot(in);
  __shared__ int cnt2[2];
  if ((t&63)==0) cnt2[t>>6] = __popcll(m);
  __syncthreads();
  if (t==0) flags[blockIdx.x] = ((cnt2[0]+cnt2[1]) > 96) ? 0 : 1; // 0 = bf16, 1 = f32
}

// flags index: 0=emb 1=pos 2=dis 3=target 4=pi 5=M 6=q 7=r 8=sc1w 9=sc1b 10=sc2w

// ---- fused: rnorm[v] = 1/max(||emb[v]||,eps) AND (f32 case) split emb -> hi/lo bf16 ----
// one wave per row, 4 rows per block
__global__ __launch_bounds__(256) void k_prep(const void* __restrict__ emb,
    float* __restrict__ rnorm, u16* __restrict__ ehi, u16* __restrict__ elo,
    const int* __restrict__ flags)
{
  int isf32 = flags[0];
  int v = blockIdx.x*4 + (threadIdx.x>>6);
  int lane = threadIdx.x & 63;
  size_t o = (size_t)v*D_ + lane*4;
  if (isf32){
    float4 q = *(const float4*)((const float*)emb + o);
    float ss = waveSum(q.x*q.x+q.y*q.y+q.z*q.z+q.w*q.w);
    if (lane==0) rnorm[v] = 1.0f/fmaxf(sqrtf(ss), 1e-12f);
    ushort4 h, l;
    h.x = f2bf(q.x); l.x = f2bf(q.x - bf2f(h.x));
    h.y = f2bf(q.y); l.y = f2bf(q.y - bf2f(h.y));
    h.z = f2bf(q.z); l.z = f2bf(q.z - bf2f(h.z));
    h.w = f2bf(q.w); l.w = f2bf(q.w - bf2f(h.w));
    *(ushort4*)(ehi+o) = h;
    *(ushort4*)(elo+o) = l;
  } else {
    uint2 p = *(const uint2*)((const u16*)emb + o);
    float a0=bflo(p.x), a1=bfhi(p.x), a2=bflo(p.y), a3=bfhi(p.y);
    float ss = waveSum(a0*a0+a1*a1+a2*a2+a3*a3);
    if (lane==0) rnorm[v] = 1.0f/fmaxf(sqrtf(ss), 1e-12f);
  }
}

// ---- GAT edge scores : one wave per edge ----
__global__ __launch_bounds__(256) void k_edge(
    const void* __restrict__ emb, const void* __restrict__ dis_emb,
    const void* __restrict__ pi_w, const void* __restrict__ M_w,
    const int* __restrict__ iid, const float* __restrict__ rnorm,
    const int* __restrict__ src, const int* __restrict__ dst, const int* __restrict__ dis,
    float* __restrict__ e_edge, const int* __restrict__ flags)
{
  int f_emb = flags[0], f_dis = flags[2], f_pi = flags[4], f_M = flags[5];
  int e = blockIdx.x*4 + (threadIdx.x>>6);
  int lane = threadIdx.x & 63;
  int s = src[e], d = dst[e], di = dis[e];
  int is = iid[s], idd = iid[d];
  float rs = rnorm[is], rd = rnorm[idd];
  int k0 = lane*4;
  float d1 = 0.f, d2 = 0.f;
  #pragma unroll
  for (int j=0;j<4;++j){
    int k = k0 + j;
    float hs = ldf(emb, (size_t)is*D_ + k, f_emb) * rs;
    float hd = ldf(emb, (size_t)idd*D_ + k, f_emb) * rd;
    float hx = ldf(dis_emb, (size_t)di*D_ + k, f_dis);
    float pr = hs*hd;
    d1 += pr * hx * ldf(pi_w, k, f_pi);
    d2 += pr * ldf(M_w, k, f_M) + hx * ldf(M_w, D_ + k, f_M);
  }
  d1 = waveSum(d1); d2 = waveSum(d2);
  if (lane==0){
    d1 = clampf(d1, -1e4f, 1e4f);
    d2 = clampf(d2, -60.f, 60.f);
    float gate = 1.0f/(1.0f+expf(-d2));
    e_edge[e] = d1*gate;
  }
}

// ---- CSR build by dst ----
__global__ __launch_bounds__(256) void k_count(const int* __restrict__ dst, int* __restrict__ cnt){
  int e = blockIdx.x*256+threadIdx.x;
  if (e<E_) atomicAdd(&cnt[dst[e]], 1);
}
__global__ __launch_bounds__(256) void k_scan(const int* __restrict__ cnt,
    int* __restrict__ offs, int* __restrict__ cursor){
  __shared__ int part[256];
  int t = threadIdx.x;
  const int CH = N_/256;
  int s = 0;
  for (int i=0;i<CH;++i) s += cnt[t*CH+i];
  part[t] = s; __syncthreads();
  if (t==0){
    int run=0;
    for (int i=0;i<256;++i){ int c=part[i]; part[i]=run; run+=c; }
    offs[N_] = run;
  }
  __syncthreads();
  int run = part[t];
  for (int i=0;i<CH;++i){ int idx=t*CH+i; offs[idx]=run; cursor[idx]=run; run+=cnt[idx]; }
}
__global__ __launch_bounds__(256) void k_scatter(const int* __restrict__ dst,
    int* __restrict__ cursor, int* __restrict__ elist){
  int e = blockIdx.x*256+threadIdx.x;
  if (e<E_){ int p = atomicAdd(&cursor[dst[e]],1); elist[p]=e; }
}

// ---- edge softmax + weighted aggregation : one block per dst node ----
__global__ __launch_bounds__(256) void k_gat(
    const void* __restrict__ emb, const int* __restrict__ iid,
    const float* __restrict__ rnorm, const float* __restrict__ e_edge,
    const int* __restrict__ offs, const int* __restrict__ elist,
    const int* __restrict__ src, float* __restrict__ hagg,
    const int* __restrict__ flags)
{
  int f_emb = flags[0];
  int n = blockIdx.x, t = threadIdx.x;
  int beg = offs[n], end = offs[n+1];
  float acc = 0.f;
  if (end > beg){
    float m = -3.0e38f;
    for (int j=beg;j<end;++j) m = fmaxf(m, e_edge[elist[j]]);
    float ssum = 0.f;
    for (int j=beg;j<end;++j) ssum += expf(e_edge[elist[j]] - m);
    float inv = 1.0f/fmaxf(ssum, 1e-30f);
    for (int j=beg;j<end;++j){
      int k = elist[j];
      int sk = src[k];
      int isk = iid[sk];
      float a = expf(e_edge[k]-m)*inv;
      acc += a * ldf(emb, (size_t)isk*D_ + t, f_emb) * rnorm[isk];
    }
  }
  hagg[(size_t)n*D_ + t] = acc;
}

// ---- f[b] = concat(h_t, last_feat) @ r_w : one block per session ----
__global__ __launch_bounds__(256) void k_f(
    const float* __restrict__ hagg, const void* __restrict__ target_emb,
    const void* __restrict__ r_w, const int* __restrict__ tid,
    const int* __restrict__ last_idx, float* __restrict__ fbuf,
    const int* __restrict__ flags)
{
  int f_t = flags[3], f_r = flags[7];
  __shared__ float scat[2*D_];
  int b = blockIdx.x, t = threadIdx.x;
  scat[t]     = ldf(target_emb, (size_t)tid[b]*D_ + t, f_t);
  scat[D_+t]  = hagg[(size_t)last_idx[b]*D_ + t];
  __syncthreads();
  float f = 0.f;
  for (int k=0;k<2*D_;++k) f += scat[k]*ldf(r_w, (size_t)k*D_ + t, f_r);
  fbuf[(size_t)b*D_ + t] = f;
}

// ---- coef : one WAVE per 8 agg edges; X rows in regs, broadcast via shfl ----
// xr[e][j] at lane L holds X_{n0+e}[L*8+j], X = [eft(256) | h_p(256)]
// lane owns t = lane*4 .. lane*4+3 output cols of eagg.
__global__ __launch_bounds__(64) void k_coef(
    const float* __restrict__ hagg, const void* __restrict__ pos_emb,
    const void* __restrict__ q_w, const float* __restrict__ fbuf,
    const int* __restrict__ pid, const int* __restrict__ agg_src,
    const int* __restrict__ agg_dst, float* __restrict__ coef,
    const int* __restrict__ flags)
{
  int f_p = flags[1], f_q = flags[6];
  int lane = threadIdx.x;
  int n0 = blockIdx.x*8;
  int t0 = lane*4;

  float xr[8][8];
  #pragma unroll
  for (int e=0;e<8;++e){
    int n = n0+e;
    if (lane < 32){
      const float* hp = hagg + (size_t)agg_src[n]*D_ + lane*8;
      float4 a = *(const float4*)hp;
      float4 b = *(const float4*)(hp+4);
      xr[e][0]=a.x; xr[e][1]=a.y; xr[e][2]=a.z; xr[e][3]=a.w;
      xr[e][4]=b.x; xr[e][5]=b.y; xr[e][6]=b.z; xr[e][7]=b.w;
    } else {
      size_t base = (size_t)pid[n]*D_ + (lane-32)*8;
      if (f_p){
        const float* pp = (const float*)pos_emb + base;
        float4 a = *(const float4*)pp;
        float4 b = *(const float4*)(pp+4);
        xr[e][0]=a.x; xr[e][1]=a.y; xr[e][2]=a.z; xr[e][3]=a.w;
        xr[e][4]=b.x; xr[e][5]=b.y; xr[e][6]=b.z; xr[e][7]=b.w;
      } else {
        const u16* pp = (const u16*)pos_emb + base;
        uint4 u = *(const uint4*)pp;
        xr[e][0]=bflo(u.x); xr[e][1]=bfhi(u.x); xr[e][2]=bflo(u.y); xr[e][3]=bfhi(u.y);
        xr[e][4]=bflo(u.z); xr[e][5]=bfhi(u.z); xr[e][6]=bflo(u.w); xr[e][7]=bfhi(u.w);
      }
    }
  }

  float y0[8], y1[8], y2[8], y3[8];
  #pragma unroll
  for (int e=0;e<8;++e){ y0[e]=0.f; y1[e]=0.f; y2[e]=0.f; y3[e]=0.f; }

  if (f_q){
    for (int kb=0; kb<64; ++kb){
      #pragma unroll
      for (int j=0;j<8;++j){
        int k = kb*8+j;
        float4 q = *(const float4*)((const float*)q_w + (size_t)k*D_ + t0);
        #pragma unroll
        for (int e=0;e<8;++e){
          float xk = __shfl(xr[e][j], kb, 64);
          y0[e] += xk*q.x; y1[e] += xk*q.y; y2[e] += xk*q.z; y3[e] += xk*q.w;
        }
      }
    }
  } else {
    for (int kb=0; kb<64; ++kb){
      #pragma unroll
      for (int j=0;j<8;++j){
        int k = kb*8+j;
        uint2 u = *(const uint2*)((const u16*)q_w + (size_t)k*D_ + t0);
        float qx=bflo(u.x), qy=bfhi(u.x), qz=bflo(u.y), qw=bfhi(u.y);
        #pragma unroll
        for (int e=0;e<8;++e){
          float xk = __shfl(xr[e][j], kb, 64);
          y0[e] += xk*qx; y1[e] += xk*qy; y2[e] += xk*qz; y3[e] += xk*qw;
        }
      }
    }
  }

  #pragma unroll
  for (int e=0;e<8;++e){
    int n = n0+e;
    int b = agg_dst[n];
    float4 f = *(const float4*)(fbuf + (size_t)b*D_ + t0);
    float s = tanhf(y0[e])*f.x + tanhf(y1[e])*f.y + tanhf(y2[e])*f.z + tanhf(y3[e])*f.w;
    s = waveSum(s);
    if (lane==0) coef[n] = clampf(s, -1e6f, 1e6f);
  }
}

// ---- sr (l2-normalized, emitted as split bf16 hi/lo) + logphi : one block per session ----
__global__ __launch_bounds__(256) void k_sr(
    const float* __restrict__ hagg, const float* __restrict__ coef,
    const void* __restrict__ sc1_w, const void* __restrict__ sc1_b,
    const void* __restrict__ sc2_w, const int* __restrict__ agg_src,
    u16* __restrict__ sr_hi, u16* __restrict__ sr_lo,
    float* __restrict__ logphi, const int* __restrict__ flags)
{
  int f_w1 = flags[8], f_b1 = flags[9], f_w2 = flags[10];
  __shared__ float ssr[D_];
  __shared__ float sred[4];
  int b = blockIdx.x, t = threadIdx.x;
  float srv = 0.f;
  for (int g=0; g<S_; ++g){
    int n = b*S_ + g;
    srv += hagg[(size_t)agg_src[n]*D_ + t] * coef[n];
  }
  float ss = blockSum(srv*srv, sred);
  float srn = srv / fmaxf(sqrtf(ss), 1e-12f);
  srn = clampf(srn, -2.f, 2.f);
  u16 h = f2bf(srn);
  sr_hi[(size_t)b*D_ + t] = h;
  sr_lo[(size_t)b*D_ + t] = f2bf(srn - bf2f(h));
  ssr[t] = srn;
  __syncthreads();
  float hid = ldf(sc1_b, t, f_b1);
  for (int k=0;k<D_;++k) hid += ssr[k]*ldf(sc1_w, (size_t)k*D_ + t, f_w1);
  hid = fmaxf(hid, 0.f);
  float z0 = blockSum(hid*ldf(sc2_w, t*2+0, f_w2), sred);
  float z1 = blockSum(hid*ldf(sc2_w, t*2+1, f_w2), sred);
  if (t==0){
    z0 = clampf(z0, -1e4f, 1e4f); z1 = clampf(z1, -1e4f, 1e4f);
    float mz = fmaxf(z0,z1);
    float lse = mz + logf(expf(z0-mz)+expf(z1-mz));
    logphi[2*b]   = z0 - lse;
    logphi[2*b+1] = z1 - lse;
  }
}

// ---- MFMA GEMM pass: x[b,v] = clamp(12 * (sr.emb_v) * rnorm[v]), Zall[b] += exp(x) ----
// Block = 128 b x 128 v. Waves split by B-ROWS: wave wv owns b [wv*32,+32), ALL 128 v.
// => all 4 waves read the SAME B addresses (3/4 of B loads are L1 hits) and only
// 4 b-chunks exist, so each B panel is fetched by at most 4 blocks.
// XCD swizzle: id -> xcd=id&7, r=id>>3, vchunk=xcd*100+(r>>2), bchunk=r&3 — the 4
// blocks of a v-chunk are consecutive ids (same XCD under round-robin), and each
// XCD owns 100 contiguous v-chunks => each B panel fetched ~once globally; sr
// panels (128KB/b-chunk) stay L2-hot. 800 v-chunks x 128 = 102400 covers V.
// ks-outer: only current-ks A frags live; acc 64 f32/lane.
// mfma_f32_16x16x32_bf16: A row=lane&15(b), B col=lane&15(v), k=(lane>>4)*8+j;
// D: col(v)=lane&15, row(b)=(lane>>4)*4+reg. NT stores keep logits out of L2/L3.
__global__ __launch_bounds__(256, 3) void k_mm(
    const void* __restrict__ emb, const u16* __restrict__ emb_hi,
    const u16* __restrict__ emb_lo, const u16* __restrict__ sr_hi,
    const u16* __restrict__ sr_lo, const float* __restrict__ rnorm,
    float* __restrict__ Zall, void* __restrict__ outp,
    const int* __restrict__ flags)
{
  int isf32 = flags[0];
  int id   = blockIdx.x;          // 0..3199
  int xcd  = id & 7;
  int r_   = id >> 3;             // 0..399
  int vch  = xcd*100 + (r_>>2);   // 0..799
  int bch  = r_ & 3;              // 0..3
  int lane = threadIdx.x & 63;
  int wv   = threadIdx.x >> 6;
  int col  = lane & 15;   // fragment 16-dim index
  int kg   = lane >> 4;   // K-group 0..3
  int bw   = bch*128 + wv*32;     // this wave's 32 b-rows
  int v0   = vch*128;

  int vr_[8];
  #pragma unroll
  for (int vt=0;vt<8;++vt){
    int vrow = v0 + vt*16 + col;
    vr_[vt] = vrow < V_ ? vrow : V_-1;
  }

  const u16* Bh  = isf32 ? emb_hi : (const u16*)emb;
  const u16* arh = sr_hi + (size_t)(bw + col)*D_ + kg*8;
  const u16* arl = sr_lo + (size_t)(bw + col)*D_ + kg*8;

  f32x4 acc[8][2];
  #pragma unroll
  for (int vt=0;vt<8;++vt){
    acc[vt][0] = (f32x4){0.f,0.f,0.f,0.f};
    acc[vt][1] = (f32x4){0.f,0.f,0.f,0.f};
  }

  if (isf32){
    #pragma unroll 1
    for (int ks=0; ks<8; ++ks){
      int ko = ks*32;
      bf16x8 ah0 = *(const bf16x8*)(arh + ko);
      bf16x8 ah1 = *(const bf16x8*)(arh + 16*D_ + ko);
      bf16x8 al0 = *(const bf16x8*)(arl + ko);
      bf16x8 al1 = *(const bf16x8*)(arl + 16*D_ + ko);
      #pragma unroll
      for (int vt=0; vt<8; ++vt){
        size_t bo = (size_t)vr_[vt]*D_ + ko + kg*8;
        bf16x8 bh = *(const bf16x8*)(Bh + bo);
        bf16x8 bl = *(const bf16x8*)(emb_lo + bo);
        acc[vt][0] = __builtin_amdgcn_mfma_f32_16x16x32_bf16(ah0, bh, acc[vt][0], 0,0,0);
        acc[vt][1] = __builtin_amdgcn_mfma_f32_16x16x32_bf16(ah1, bh, acc[vt][1], 0,0,0);
        acc[vt][0] = __builtin_amdgcn_mfma_f32_16x16x32_bf16(al0, bh, acc[vt][0], 0,0,0);
        acc[vt][1] = __builtin_amdgcn_mfma_f32_16x16x32_bf16(al1, bh, acc[vt][1], 0,0,0);
        acc[vt][0] = __builtin_amdgcn_mfma_f32_16x16x32_bf16(ah0, bl, acc[vt][0], 0,0,0);
        acc[vt][1] = __builtin_amdgcn_mfma_f32_16x16x32_bf16(ah1, bl, acc[vt][1], 0,0,0);
      }
    }
  } else {
    #pragma unroll 1
    for (int ks=0; ks<8; ++ks){
      int ko = ks*32;
      bf16x8 ah0 = *(const bf16x8*)(arh + ko);
      bf16x8 ah1 = *(const bf16x8*)(arh + 16*D_ + ko);
      bf16x8 al0 = *(const bf16x8*)(arl + ko);
      bf16x8 al1 = *(const bf16x8*)(arl + 16*D_ + ko);
      #pragma unroll
      for (int vt=0; vt<8; ++vt){
        size_t bo = (size_t)vr_[vt]*D_ + ko + kg*8;
        bf16x8 bh = *(const bf16x8*)(Bh + bo);
        acc[vt][0] = __builtin_amdgcn_mfma_f32_16x16x32_bf16(ah0, bh, acc[vt][0], 0,0,0);
        acc[vt][1] = __builtin_amdgcn_mfma_f32_16x16x32_bf16(ah1, bh, acc[vt][1], 0,0,0);
        acc[vt][0] = __builtin_amdgcn_mfma_f32_16x16x32_bf16(al0, bh, acc[vt][0], 0,0,0);
        acc[vt][1] = __builtin_amdgcn_mfma_f32_16x16x32_bf16(al1, bh, acc[vt][1], 0,0,0);
      }
    }
  }

  // epilogue: scale, clamp, exp-accumulate, non-temporal store
  float zs[2][4];
  #pragma unroll
  for (int m=0;m<2;++m){ zs[m][0]=0.f; zs[m][1]=0.f; zs[m][2]=0.f; zs[m][3]=0.f; }

  #pragma unroll
  for (int vt=0; vt<8; ++vt){
    int vrow = v0 + vt*16 + col;
    bool ok = vrow < V_;
    float rv = rnorm[vr_[vt]] * SCALE_;
    #pragma unroll
    for (int m=0;m<2;++m){
      #pragma unroll
      for (int r=0;r<4;++r){
        float x = clampf(acc[vt][m][r]*rv, -40.f, 40.f);
        if (ok){
          zs[m][r] += expf(x);
          int b = bw + m*16 + kg*4 + r;
          if (isf32) __builtin_nontemporal_store(x, (float*)outp + (size_t)b*V_ + vrow);
          else       __builtin_nontemporal_store(f2bf(x), (u16*)outp + (size_t)b*V_ + vrow);
        }
      }
    }
  }
  // reduce zs across the 16 col-lanes (same kg), then one atomic per b
  #pragma unroll
  for (int m=0;m<2;++m){
    #pragma unroll
    for (int r=0;r<4;++r){
      float z = zs[m][r];
      z += __shfl_xor(z, 1, 64);
      z += __shfl_xor(z, 2, 64);
      z += __shfl_xor(z, 4, 64);
      z += __shfl_xor(z, 8, 64);
      if (col==0) atomicAdd(&Zall[bw + m*16 + kg*4 + r], z);
    }
  }
}

// ---- save logits at masked positions (before k_out clobbers them) ----
__global__ __launch_bounds__(256) void k_pre(const int* __restrict__ iid,
    const int* __restrict__ agg_dst, const void* __restrict__ outp,
    float* __restrict__ xsave, const int* __restrict__ flags)
{
  int isf32 = flags[0];
  int n = blockIdx.x*256 + threadIdx.x;
  if (n < N_){
    int b = agg_dst[n];
    int v = iid[n];
    xsave[n] = rdout(outp, (size_t)b*V_ + v, isf32);
  }
}

// ---- Zin[b] = sum over UNIQUE masked v of exp(x) ----
__global__ __launch_bounds__(64) void k_zin(const int* __restrict__ iid,
    const float* __restrict__ xsave, float* __restrict__ Zin)
{
  __shared__ int ids[S_];
  int b = blockIdx.x, g = threadIdx.x;
  if (g < S_) ids[g] = iid[b*S_ + g];
  __syncthreads();
  float z = 0.f;
  if (g < S_){
    bool first = true;
    for (int h=0; h<g; ++h) if (ids[h]==ids[g]){ first=false; break; }
    if (first) z = expf(clampf(xsave[b*S_+g], -40.f, 40.f));
  }
  z = waveSum(z);
  if (g==0) Zin[b] = z;
}

__global__ __launch_bounds__(256) void k_fin(const float* __restrict__ logphi,
    const float* __restrict__ Zall, const float* __restrict__ Zin,
    float* __restrict__ cin, float* __restrict__ cex)
{
  int b = blockIdx.x*256+threadIdx.x;
  if (b < B_){
    float zin = Zin[b];
    float zex = Zall[b] - zin;
    cin[b] = clampf(logphi[2*b]   - logf(fmaxf(zin, 1e-30f)), -1e4f, 1e4f);
    cex[b] = clampf(logphi[2*b+1] - logf(fmaxf(zex, 1e-30f)), -1e4f, 1e4f);
  }
}

// ---- pass 2: out = x + cex for ALL positions (masked fixed up by k_patch) ----
// non-temporal both ways (ext-vector types): pure stream, nothing re-reads it
__global__ __launch_bounds__(256) void k_out(const float* __restrict__ cex,
    void* __restrict__ outp, const int* __restrict__ flags)
{
  int isf32 = flags[0];
  int b = blockIdx.y;
  int v0 = (blockIdx.x*256 + threadIdx.x)*4;
  if (v0 >= V_) return;
  float ce = cex[b];
  if (isf32){
    float* p = (float*)outp + (size_t)b*V_ + v0;
    f32x4 x = __builtin_nontemporal_load((const f32x4*)p);
    x[0] = clampf(x[0]+ce, -1e4f, 1e4f); x[1] = clampf(x[1]+ce, -1e4f, 1e4f);
    x[2] = clampf(x[2]+ce, -1e4f, 1e4f); x[3] = clampf(x[3]+ce, -1e4f, 1e4f);
    __builtin_nontemporal_store(x, (f32x4*)p);
  } else {
    u16* p = (u16*)outp + (size_t)b*V_ + v0;
    u16x4 lg = __builtin_nontemporal_load((const u16x4*)p);
    lg[0] = f2bf(clampf(bf2f(lg[0])+ce, -1e4f, 1e4f));
    lg[1] = f2bf(clampf(bf2f(lg[1])+ce, -1e4f, 1e4f));
    lg[2] = f2bf(clampf(bf2f(lg[2])+ce, -1e4f, 1e4f));
    lg[3] = f2bf(clampf(bf2f(lg[3])+ce, -1e4f, 1e4f));
    __builtin_nontemporal_store(lg, (u16x4*)p);
  }
}

// ---- fix up masked positions: out[b, iid[n]] = xsave[n] + cin[b] ----
__global__ __launch_bounds__(256) void k_patch(const int* __restrict__ iid,
    const int* __restrict__ agg_dst, const float* __restrict__ xsave,
    const float* __restrict__ cin, void* __restrict__ outp,
    const int* __restrict__ flags)
{
  int isf32 = flags[0];
  int n = blockIdx.x*256 + threadIdx.x;
  if (n < N_){
    int b = agg_dst[n];
    int v = iid[n];
    float val = clampf(xsave[n] + cin[b], -1e4f, 1e4f);
    stout(outp, (size_t)b*V_ + v, val, isf32);
  }
}

extern "C" void kernel_launch(void* const* d_in, const int* in_sizes, int n_in,
                              void* d_out, int out_size, void* d_ws, size_t ws_size,
                              hipStream_t stream)
{
  (void)in_sizes; (void)n_in; (void)out_size; (void)ws_size;
  const int* iid      = (const int*)d_in[0];
  const int* src      = (const int*)d_in[1];
  const int* dst      = (const int*)d_in[2];
  const int* dis      = (const int*)d_in[3];
  const int* pid      = (const int*)d_in[4];
  const int* agg_src  = (const int*)d_in[5];
  const int* agg_dst  = (const int*)d_in[6];
  const int* tid      = (const int*)d_in[7];
  const int* last_idx = (const int*)d_in[8];
  const void* emb        = d_in[9];
  const void* pos_emb    = d_in[10];
  const void* dis_emb    = d_in[11];
  const void* target_emb = d_in[12];
  const void* pi_w  = d_in[13];
  const void* M_w   = d_in[14];
  const void* q_w   = d_in[15];
  const void* r_w   = d_in[16];
  const void* sc1_w = d_in[17];
  const void* sc1_b = d_in[18];
  const void* sc2_w = d_in[19];

  char* w = (char*)d_ws;
  size_t off = 0;
  auto alloc = [&](size_t bytes)->char*{
    char* p = w + off;
    off = (off + bytes + 255) & ~(size_t)255;
    return p;
  };
  // total ws use: ~116 MB (emb hi/lo planes dominate)
  int*   flags  = (int*)alloc(16*4);
  float* rnorm  = (float*)alloc((size_t)V_*4);        // 0.40 MB
  float* hagg   = (float*)alloc((size_t)N_*D_*4);     // 10.49 MB
  float* e_edge = (float*)alloc((size_t)E_*4);        // 0.33 MB
  int*   cnt    = (int*)alloc((size_t)N_*4);
  int*   offs   = (int*)alloc((size_t)(N_+1)*4);
  int*   cursor = (int*)alloc((size_t)N_*4);
  int*   elist  = (int*)alloc((size_t)E_*4);          // 0.33 MB
  float* fbuf   = (float*)alloc((size_t)B_*D_*4);     // 0.52 MB
  float* coef   = (float*)alloc((size_t)N_*4);
  u16*   sr_hi  = (u16*)alloc((size_t)B_*D_*2);       // 0.26 MB
  u16*   sr_lo  = (u16*)alloc((size_t)B_*D_*2);       // 0.26 MB
  float* logphi = (float*)alloc((size_t)2*B_*4);
  float* Zall   = (float*)alloc((size_t)B_*4);
  float* Zin    = (float*)alloc((size_t)B_*4);
  float* cin    = (float*)alloc((size_t)B_*4);
  float* cex    = (float*)alloc((size_t)B_*4);
  float* xsave  = (float*)alloc((size_t)N_*4);
  u16*   emb_hi = (u16*)alloc((size_t)V_*D_*2);       // 51.2 MB
  u16*   emb_lo = (u16*)alloc((size_t)V_*D_*2);       // 51.2 MB

  hipMemsetAsync(cnt, 0, (size_t)N_*4, stream);
  hipMemsetAsync(Zall, 0, (size_t)B_*4, stream);

  k_detect <<<11, 128, 0, stream>>>((const u32*)emb, (const u32*)pos_emb,
             (const u32*)dis_emb, (const u32*)target_emb, (const u32*)pi_w,
             (const u32*)M_w, (const u32*)q_w, (const u32*)r_w,
             (const u32*)sc1_w, (const u32*)sc1_b, (const u32*)sc2_w, flags);
  k_prep   <<<V_/4, 256, 0, stream>>>(emb, rnorm, emb_hi, emb_lo, flags);
  k_edge   <<<E_/4, 256, 0, stream>>>(emb, dis_emb, pi_w, M_w, iid, rnorm,
                                      src, dst, dis, e_edge, flags);
  k_count  <<<E_/256, 256, 0, stream>>>(dst, cnt);
  k_scan   <<<1, 256, 0, stream>>>(cnt, offs, cursor);
  k_scatter<<<E_/256, 256, 0, stream>>>(dst, cursor, elist);
  k_gat    <<<N_, 256, 0, stream>>>(emb, iid, rnorm, e_edge, offs, elist, src, hagg, flags);
  k_f      <<<B_, 256, 0, stream>>>(hagg, target_emb, r_w, tid, last_idx, fbuf, flags);
  k_coef   <<<N_/8, 64, 0, stream>>>(hagg, pos_emb, q_w, fbuf, pid, agg_src, agg_dst, coef, flags);
  k_sr     <<<B_, 256, 0, stream>>>(hagg, coef, sc1_w, sc1_b, sc2_w, agg_src,
                                    sr_hi, sr_lo, logphi, flags);
  k_mm     <<<3200, 256, 0, stream>>>(emb, emb_hi, emb_lo, sr_hi, sr_lo,
                                      rnorm, Zall, d_out, flags);
  k_pre    <<<(N_+255)/256, 256, 0, stream>>>(iid, agg_dst, d_out, xsave, flags);
  k_zin    <<<B_, 64, 0, stream>>>(iid, xsave, Zin);
  k_fin    <<<(B_+255)/256, 256, 0, stream>>>(logphi, Zall, Zin, cin, cex);
  k_out    <<<dim3((V_/4+255)/256, B_), 256, 0, stream>>>(cex, d_out, flags);
  k_patch  <<<(N_+255)/256, 256, 0, stream>>>(iid, agg_dst, xsave, cin, d_out, flags);
}